// Round 1
// baseline (467.834 us; speedup 1.0000x reference)
//
#include <hip/hip_runtime.h>
#include <hip/hip_bf16.h>
#include <stdint.h>

// QLSTM: T=256, B=2048, DIN=128, NQ=16, 4 gates. fp32 inputs, fp32 outputs.
// Pipeline: (1) MFMA GEMM projecting x -> xz[T*B,64] (+b+theta folded), hi/lo bf16 split
//           (2) recurrent scan, one wave per batch element, lane = (gate,qubit).
//               R5: h-dot via 15 parallel DPP row_ror rotates + permuted weights
//                   (replaces 16 ds_swizzle broadcasts -> no LDS wait in dot),
//                   explicit ds_bpermute with hoisted addresses for f/i/g/o,
//                   dtype detect folded into each kernel (detect launch removed).

#define T_STEPS 256
#define BATCH   2048
#define DIN     128
#define NQ      16
#define LCOLS   64          // 4 gates * 16 qubits
#define DTOT    144         // DIN + NQ
#define ROWS    (T_STEPS * BATCH)   // 524288
#define MTILES  (ROWS / 16)         // 32768

typedef __attribute__((ext_vector_type(8))) short bf16x8;
typedef __attribute__((ext_vector_type(4))) float f32x4;

__device__ __forceinline__ float bf2f(unsigned short u) {
    union { unsigned int i; float f; } v; v.i = ((unsigned int)u) << 16; return v.f;
}
__device__ __forceinline__ unsigned short f2bf(float f) {
    union { float f; unsigned int i; } v; v.f = f;
    unsigned int i = v.i;
    unsigned int r = i + 0x7fffu + ((i >> 16) & 1u);   // round-nearest-even
    return (unsigned short)(r >> 16);
}

__device__ __forceinline__ float ldval(const float* p) { return *p; }
__device__ __forceinline__ float ldval(const unsigned short* p) { return bf2f(*p); }
__device__ __forceinline__ void stval(float* p, float v) { *p = v; }
__device__ __forceinline__ void stval(unsigned short* p, float v) { *p = f2bf(v); }

// ---------------- per-wave dtype detector (bf16=1, fp32=0), wave-uniform ----------------
// exponent-field histogram over first 256 words of x: bf16 pairs ~256 hits, fp32 ~41.
__device__ __forceinline__ int detect_bf16(const unsigned int* __restrict__ xw, int lane) {
    int cnt = 0;
#pragma unroll
    for (int i = 0; i < 4; ++i) {
        unsigned int w = xw[lane + i * 64];
        unsigned int e = (w >> 7) & 0xFFu;
        cnt += (e >= 100u && e <= 140u) ? 1 : 0;
    }
#pragma unroll
    for (int d = 32; d > 0; d >>= 1) cnt += __shfl_down(cnt, d, 64);
    int tot = __shfl(cnt, 0, 64);
    return (tot >= 140) ? 1 : 0;
}

// ---------------- Kernel 1: x-projection GEMM (MFMA bf16 16x16x32) ----------------
template <typename OutT>
__global__ __launch_bounds__(256) void qlstm_proj(
    const void* __restrict__ x_, const void* __restrict__ W_,
    const void* __restrict__ b_, const void* __restrict__ th_,
    OutT* __restrict__ xz)
{
    const int lane  = threadIdx.x & 63;
    const int isbf  = __builtin_amdgcn_readfirstlane(detect_bf16((const unsigned int*)x_, lane));
    const int wid   = blockIdx.x * (blockDim.x >> 6) + (threadIdx.x >> 6);
    const int nwv   = gridDim.x * (blockDim.x >> 6);
    const int m     = lane & 15;
    const int quad  = lane >> 4;

    if (isbf) {
        const unsigned short* x  = (const unsigned short*)x_;
        const unsigned short* W  = (const unsigned short*)W_;
        const unsigned short* bv = (const unsigned short*)b_;
        const unsigned short* th = (const unsigned short*)th_;
        bf16x8 bfrag[4][4];
#pragma unroll
        for (int kt = 0; kt < 4; ++kt)
#pragma unroll
            for (int nb = 0; nb < 4; ++nb)
                bfrag[kt][nb] = *(const bf16x8*)(W + (size_t)(nb * 16 + m) * DTOT + kt * 32 + quad * 8);
        float bias[4];
#pragma unroll
        for (int nb = 0; nb < 4; ++nb) {
            int col = nb * 16 + m;
            bias[nb] = bf2f(bv[col]) + bf2f(th[col]);
        }
        for (int mt = wid; mt < MTILES; mt += nwv) {
            const int row0 = mt * 16;
            const unsigned short* xp = x + (size_t)(row0 + m) * DIN + quad * 8;
            bf16x8 a[4];
#pragma unroll
            for (int kt = 0; kt < 4; ++kt) a[kt] = *(const bf16x8*)(xp + kt * 32);
            f32x4 acc[4] = {};
#pragma unroll
            for (int kt = 0; kt < 4; ++kt)
#pragma unroll
                for (int nb = 0; nb < 4; ++nb)
                    acc[nb] = __builtin_amdgcn_mfma_f32_16x16x32_bf16(a[kt], bfrag[kt][nb], acc[nb], 0, 0, 0);
#pragma unroll
            for (int nb = 0; nb < 4; ++nb) {
                int col = nb * 16 + m;
#pragma unroll
                for (int r = 0; r < 4; ++r)
                    stval(xz + (size_t)(row0 + quad * 4 + r) * LCOLS + col, acc[nb][r] + bias[nb]);
            }
        }
    } else {
        const float* x  = (const float*)x_;
        const float* W  = (const float*)W_;
        const float* bv = (const float*)b_;
        const float* th = (const float*)th_;
        bf16x8 bhi[4][4], blo[4][4];
#pragma unroll
        for (int kt = 0; kt < 4; ++kt)
#pragma unroll
            for (int nb = 0; nb < 4; ++nb) {
                const float* p = W + (size_t)(nb * 16 + m) * DTOT + kt * 32 + quad * 8;
#pragma unroll
                for (int j = 0; j < 8; ++j) {
                    float w = p[j];
                    unsigned short h = f2bf(w);
                    bhi[kt][nb][j] = (short)h;
                    blo[kt][nb][j] = (short)f2bf(w - bf2f(h));
                }
            }
        float bias[4];
#pragma unroll
        for (int nb = 0; nb < 4; ++nb) {
            int col = nb * 16 + m;
            bias[nb] = bv[col] + th[col];
        }
        for (int mt = wid; mt < MTILES; mt += nwv) {
            const int row0 = mt * 16;
            const float* xp = x + (size_t)(row0 + m) * DIN + quad * 8;
            f32x4 xr[8];
#pragma unroll
            for (int kt = 0; kt < 4; ++kt) {
                xr[2 * kt]     = *(const f32x4*)(xp + kt * 32);
                xr[2 * kt + 1] = *(const f32x4*)(xp + kt * 32 + 4);
            }
            f32x4 acc[4] = {};
#pragma unroll
            for (int kt = 0; kt < 4; ++kt) {
                bf16x8 ah, al;
#pragma unroll
                for (int j = 0; j < 8; ++j) {
                    float xv = xr[2 * kt + (j >> 2)][j & 3];
                    unsigned short h = f2bf(xv);
                    ah[j] = (short)h;
                    al[j] = (short)f2bf(xv - bf2f(h));
                }
#pragma unroll
                for (int nb = 0; nb < 4; ++nb)
                    acc[nb] = __builtin_amdgcn_mfma_f32_16x16x32_bf16(ah, bhi[kt][nb], acc[nb], 0, 0, 0);
#pragma unroll
                for (int nb = 0; nb < 4; ++nb)
                    acc[nb] = __builtin_amdgcn_mfma_f32_16x16x32_bf16(al, bhi[kt][nb], acc[nb], 0, 0, 0);
#pragma unroll
                for (int nb = 0; nb < 4; ++nb)
                    acc[nb] = __builtin_amdgcn_mfma_f32_16x16x32_bf16(ah, blo[kt][nb], acc[nb], 0, 0, 0);
            }
#pragma unroll
            for (int nb = 0; nb < 4; ++nb) {
                int col = nb * 16 + m;
#pragma unroll
                for (int r = 0; r < 4; ++r)
                    stval(xz + (size_t)(row0 + quad * 4 + r) * LCOLS + col, acc[nb][r] + bias[nb]);
            }
        }
    }
}

// ---------------- Kernel 2: recurrent scan ----------------
// DPP shift-by-CTRL with multiplicative identity fill (width-16 shfl_up equivalent)
template <int CTRL>
__device__ __forceinline__ float dpp_sh(float v) {
    int r = __builtin_amdgcn_update_dpp(__builtin_bit_cast(int, 1.0f),
                                        __builtin_bit_cast(int, v),
                                        CTRL, 0xF, 0xF, false);
    return __builtin_bit_cast(float, r);
}
// DPP row_ror:k rotate within each 16-lane row (pure VALU, no LDS)
template <int CTRL>
__device__ __forceinline__ float rot16(float v) {
    int r = __builtin_amdgcn_update_dpp(0, __builtin_bit_cast(int, v),
                                        CTRL, 0xF, 0xF, false);
    return __builtin_bit_cast(float, r);
}

template <int BASE>
__device__ __forceinline__ void qstep(int t, int g, int n, float cur,
                                      const float (&Wp)[16], float& h, float& c,
                                      float& hsave, float* __restrict__ out, int b,
                                      int a_f, int a_i, int a_g, int a_o)
{
    // h-dot: 15 independent DPP rotates (no LDS); Wp is pre-permuted so
    // Wp[k] pairs with h_{(n +/- k) & 15} delivered by row_ror:k.
    float h1  = rot16<0x121>(h), h2  = rot16<0x122>(h), h3  = rot16<0x123>(h);
    float h4  = rot16<0x124>(h), h5  = rot16<0x125>(h), h6  = rot16<0x126>(h), h7  = rot16<0x127>(h);
    float h8  = rot16<0x128>(h), h9  = rot16<0x129>(h), h10 = rot16<0x12A>(h), h11 = rot16<0x12B>(h);
    float h12 = rot16<0x12C>(h), h13 = rot16<0x12D>(h), h14 = rot16<0x12E>(h), h15 = rot16<0x12F>(h);

    float s0 = fmaf(Wp[0],  h,   fmaf(Wp[1],  h1,  fmaf(Wp[2],  h2,  Wp[3]  * h3)));
    float s1 = fmaf(Wp[4],  h4,  fmaf(Wp[5],  h5,  fmaf(Wp[6],  h6,  Wp[7]  * h7)));
    float s2 = fmaf(Wp[8],  h8,  fmaf(Wp[9],  h9,  fmaf(Wp[10], h10, Wp[11] * h11)));
    float s3 = fmaf(Wp[12], h12, fmaf(Wp[13], h13, fmaf(Wp[14], h14, Wp[15] * h15)));
    float z = cur + ((s0 + s1) + (s2 + s3));

    float cz = __cosf(z);
    // inclusive prefix product over the 16-lane row (DPP Hillis-Steele)
    cz *= dpp_sh<BASE + 1>(cz);
    cz *= dpp_sh<BASE + 2>(cz);
    cz *= dpp_sh<BASE + 4>(cz);
    cz *= dpp_sh<BASE + 8>(cz);

    float a = (g == 2) ? 2.f * cz : cz;
    float e = __expf(-a);
    float rr = __builtin_amdgcn_rcpf(1.f + e);
    float s = (g == 2) ? (1.f - e) * rr : rr;

    int si = __builtin_bit_cast(int, s);
    float fv = __builtin_bit_cast(float, __builtin_amdgcn_ds_bpermute(a_f, si));
    float iv = __builtin_bit_cast(float, __builtin_amdgcn_ds_bpermute(a_i, si));
    float gv = __builtin_bit_cast(float, __builtin_amdgcn_ds_bpermute(a_g, si));
    float ov = __builtin_bit_cast(float, __builtin_amdgcn_ds_bpermute(a_o, si));

    c = fmaf(fv, c, iv * gv);
    float e2 = __expf(-2.f * c);
    float tc = (1.f - e2) * __builtin_amdgcn_rcpf(1.f + e2);
    h = ov * tc;

    if ((t & 3) == g) hsave = h;
    if ((t & 3) == 3)
        out[(size_t)(t - 3 + g) * (BATCH * NQ) + (size_t)b * NQ + n] = hsave;
}

template <int BASE, typename InT>
__device__ __forceinline__ void scan_main(const InT* __restrict__ xz,
                                          float* __restrict__ out,
                                          int b, int lane, const float (&Wp)[16])
{
    const int g = lane >> 4, n = lane & 15;
    const int a_f = n << 2, a_i = (16 + n) << 2, a_g = (32 + n) << 2, a_o = (48 + n) << 2;
    float h = 0.f, c = 0.f, hsave = 0.f;
    const InT* xp = xz + (size_t)b * LCOLS + lane;
    const size_t ts = (size_t)BATCH * LCOLS;    // stride between timesteps

    float A[8], Bb[8];
#pragma unroll
    for (int j = 0; j < 8; ++j) A[j] = ldval(xp + (size_t)j * ts);

    for (int ch = 0; ch < 32; ch += 2) {
        const InT* pn = xp + (size_t)(ch + 1) * 8 * ts;
#pragma unroll
        for (int j = 0; j < 8; ++j) Bb[j] = ldval(pn + (size_t)j * ts);
#pragma unroll
        for (int j = 0; j < 8; ++j)
            qstep<BASE>(ch * 8 + j, g, n, A[j], Wp, h, c, hsave, out, b, a_f, a_i, a_g, a_o);
        if (ch + 2 < 32) {
            const InT* pa = xp + (size_t)(ch + 2) * 8 * ts;
#pragma unroll
            for (int j = 0; j < 8; ++j) A[j] = ldval(pa + (size_t)j * ts);
        }
#pragma unroll
        for (int j = 0; j < 8; ++j)
            qstep<BASE>((ch + 1) * 8 + j, g, n, Bb[j], Wp, h, c, hsave, out, b, a_f, a_i, a_g, a_o);
    }

    if (g == 0) {
        out[(size_t)T_STEPS * BATCH * NQ + (size_t)b * NQ + n] = h;                       // hx
        out[(size_t)T_STEPS * BATCH * NQ + (size_t)BATCH * NQ + (size_t)b * NQ + n] = c;  // cx
    }
}

template <typename InT>
__global__ __launch_bounds__(256) void qlstm_scan(
    const void* __restrict__ x_, const void* __restrict__ W_,
    const InT* __restrict__ xz, float* __restrict__ out)
{
    const int lane = threadIdx.x & 63;
    const int b    = blockIdx.x * (blockDim.x >> 6) + (threadIdx.x >> 6);
    const int n    = lane & 15;
    const int isbf = __builtin_amdgcn_readfirstlane(detect_bf16((const unsigned int*)x_, lane));

    // runtime probe of DPP row_ror direction (wave-uniform):
    // after ror:1, lane 0 holds 1  -> lane p receives from (p+1)&15  -> idx step +1
    // after ror:1, lane 0 holds 15 -> lane p receives from (p-1)&15  -> idx step -1 (=+15)
    int pr  = __builtin_amdgcn_update_dpp(0, lane, 0x121, 0xF, 0xF, false);
    int p0r = __shfl(pr, 0, 64);
    const int d = (p0r == 1) ? 1 : 15;

    float Wp[16];
    if (isbf) {
        const unsigned short* W = (const unsigned short*)W_;
#pragma unroll
        for (int k = 0; k < 16; ++k)
            Wp[k] = bf2f(W[(size_t)lane * DTOT + DIN + ((n + k * d) & 15)]);
    } else {
        const float* W = (const float*)W_;
#pragma unroll
        for (int k = 0; k < 16; ++k)
            Wp[k] = W[(size_t)lane * DTOT + DIN + ((n + k * d) & 15)];
    }

    // runtime probe of DPP row_shr direction (wave-uniform) for the prefix product
    int probe = __builtin_amdgcn_update_dpp(999, lane, 0x111, 0xF, 0xF, false);
    int p2 = __shfl(probe, 2, 64);
    if (p2 == 1) scan_main<0x110>(xz, out, b, lane, Wp);   // row_shr = from lane-i-N (expected)
    else         scan_main<0x100>(xz, out, b, lane, Wp);   // flipped semantics -> row_shl
}

extern "C" void kernel_launch(void* const* d_in, const int* in_sizes, int n_in,
                              void* d_out, int out_size, void* d_ws, size_t ws_size,
                              hipStream_t stream) {
    const void* x  = d_in[0];
    const void* W  = d_in[1];
    const void* bv = d_in[2];
    const void* th = d_in[3];
    float* out = (float*)d_out;

    const size_t need_f32 = (size_t)ROWS * LCOLS * sizeof(float);  // 128 MiB
    if (ws_size >= need_f32) {
        float* xz = (float*)d_ws;
        qlstm_proj<float><<<1024, 256, 0, stream>>>(x, W, bv, th, xz);
        qlstm_scan<float><<<BATCH / 4, 256, 0, stream>>>(x, W, xz, out);
    } else {
        unsigned short* xz = (unsigned short*)d_ws;
        qlstm_proj<unsigned short><<<1024, 256, 0, stream>>>(x, W, bv, th, xz);
        qlstm_scan<unsigned short><<<BATCH / 4, 256, 0, stream>>>(x, W, xz, out);
    }
}

// Round 2
// 441.699 us; speedup vs baseline: 1.0592x; 1.0592x over previous
//
#include <hip/hip_runtime.h>
#include <hip/hip_bf16.h>
#include <stdint.h>

// QLSTM: T=256, B=2048, DIN=128, NQ=16, 4 gates. fp32 inputs, fp32 outputs.
// R6: single fused kernel. Block = 4 waves = 4 batches. Per 4-step chunk the
// block computes the 16x64 x-projection with MFMA (rows = 4t x 4b, K=128,
// hi/lo bf16 split for fp32 inputs) into a double-buffered LDS z-tile, then
// each wave advances its batch's recurrence 4 steps. Eliminates the 128 MiB
// xz write + 128 MiB xz read of the previous two-kernel pipeline.

#define T_STEPS 256
#define BATCH   2048
#define DIN     128
#define NQ      16
#define LCOLS   64          // 4 gates * 16 qubits
#define DTOT    144         // DIN + NQ
#define NCH     64          // T_STEPS / 4 chunks
#define CH_XSTRIDE ((size_t)4 * BATCH * DIN)   // x elements per chunk

typedef __attribute__((ext_vector_type(8))) short bf16x8;
typedef __attribute__((ext_vector_type(4))) float f32x4;

__device__ __forceinline__ float bf2f(unsigned short u) {
    union { unsigned int i; float f; } v; v.i = ((unsigned int)u) << 16; return v.f;
}
__device__ __forceinline__ unsigned short f2bf(float f) {
    union { float f; unsigned int i; } v; v.f = f;
    unsigned int i = v.i;
    unsigned int r = i + 0x7fffu + ((i >> 16) & 1u);   // round-nearest-even
    return (unsigned short)(r >> 16);
}
__device__ __forceinline__ float ldval(const float* p) { return *p; }
__device__ __forceinline__ float ldval(const unsigned short* p) { return bf2f(*p); }

// ---------------- per-wave dtype detector (bf16=1, fp32=0), wave-uniform ----------------
__device__ __forceinline__ int detect_bf16(const unsigned int* __restrict__ xw, int lane) {
    int cnt = 0;
#pragma unroll
    for (int i = 0; i < 4; ++i) {
        unsigned int w = xw[lane + i * 64];
        unsigned int e = (w >> 7) & 0xFFu;
        cnt += (e >= 100u && e <= 140u) ? 1 : 0;
    }
#pragma unroll
    for (int d = 32; d > 0; d >>= 1) cnt += __shfl_down(cnt, d, 64);
    int tot = __shfl(cnt, 0, 64);
    return (tot >= 140) ? 1 : 0;
}

// ---------------- DPP helpers ----------------
template <int CTRL>
__device__ __forceinline__ float dpp_sh(float v) {   // shift w/ multiplicative identity
    int r = __builtin_amdgcn_update_dpp(__builtin_bit_cast(int, 1.0f),
                                        __builtin_bit_cast(int, v),
                                        CTRL, 0xF, 0xF, false);
    return __builtin_bit_cast(float, r);
}
template <int CTRL>
__device__ __forceinline__ float rot16(float v) {    // row rotate (pure VALU)
    int r = __builtin_amdgcn_update_dpp(0, __builtin_bit_cast(int, v),
                                        CTRL, 0xF, 0xF, false);
    return __builtin_bit_cast(float, r);
}

// ---------------- one recurrence step ----------------
template <int BASE>
__device__ __forceinline__ void qstep(int t, int g, int n, float cur,
                                      const float (&Wp)[16], float& h, float& c,
                                      float& hsave, float* __restrict__ out, int b,
                                      int a_f, int a_i, int a_g, int a_o)
{
    float h1  = rot16<0x121>(h), h2  = rot16<0x122>(h), h3  = rot16<0x123>(h);
    float h4  = rot16<0x124>(h), h5  = rot16<0x125>(h), h6  = rot16<0x126>(h), h7  = rot16<0x127>(h);
    float h8  = rot16<0x128>(h), h9  = rot16<0x129>(h), h10 = rot16<0x12A>(h), h11 = rot16<0x12B>(h);
    float h12 = rot16<0x12C>(h), h13 = rot16<0x12D>(h), h14 = rot16<0x12E>(h), h15 = rot16<0x12F>(h);

    float s0 = fmaf(Wp[0],  h,   fmaf(Wp[1],  h1,  fmaf(Wp[2],  h2,  Wp[3]  * h3)));
    float s1 = fmaf(Wp[4],  h4,  fmaf(Wp[5],  h5,  fmaf(Wp[6],  h6,  Wp[7]  * h7)));
    float s2 = fmaf(Wp[8],  h8,  fmaf(Wp[9],  h9,  fmaf(Wp[10], h10, Wp[11] * h11)));
    float s3 = fmaf(Wp[12], h12, fmaf(Wp[13], h13, fmaf(Wp[14], h14, Wp[15] * h15)));
    float z = cur + ((s0 + s1) + (s2 + s3));

    float cz = __cosf(z);
    cz *= dpp_sh<BASE + 1>(cz);
    cz *= dpp_sh<BASE + 2>(cz);
    cz *= dpp_sh<BASE + 4>(cz);
    cz *= dpp_sh<BASE + 8>(cz);

    float a = (g == 2) ? 2.f * cz : cz;
    float e = __expf(-a);
    float rr = __builtin_amdgcn_rcpf(1.f + e);
    float s = (g == 2) ? (1.f - e) * rr : rr;

    int si = __builtin_bit_cast(int, s);
    float fv = __builtin_bit_cast(float, __builtin_amdgcn_ds_bpermute(a_f, si));
    float iv = __builtin_bit_cast(float, __builtin_amdgcn_ds_bpermute(a_i, si));
    float gv = __builtin_bit_cast(float, __builtin_amdgcn_ds_bpermute(a_g, si));
    float ov = __builtin_bit_cast(float, __builtin_amdgcn_ds_bpermute(a_o, si));

    c = fmaf(fv, c, iv * gv);
    float e2 = __expf(-2.f * c);
    float tc = (1.f - e2) * __builtin_amdgcn_rcpf(1.f + e2);
    h = ov * tc;

    if ((t & 3) == g) hsave = h;
    if ((t & 3) == 3)
        out[(size_t)(t - 3 + g) * (BATCH * NQ) + (size_t)b * NQ + n] = hsave;
}

// ---------------- fused main ----------------
// xshv slot(row, kt, q, s) = ((row*4 + kt)*4 + q)*2 + s   (bf16x8 units)
template <int BASE, typename InT>
__device__ __forceinline__ void fused_main(
    const InT* __restrict__ x, const InT* __restrict__ W,
    const InT* __restrict__ bv, const InT* __restrict__ th,
    float* __restrict__ out, int b0, int w, int lane,
    const float (&Wp)[16], float (*zbuf)[16][64], bf16x8* __restrict__ xshv)
{
    const int m = lane & 15, quad = lane >> 4;
    const int g = quad, n = m;
    const int b = b0 + w;
    const int a_f = n << 2, a_i = (16 + n) << 2, a_g = (32 + n) << 2, a_o = (48 + n) << 2;

    // B-fragments: W cols w*16 + m (this wave's output quarter), hi/lo for fp32
    bf16x8 bh[4], bl[4];
    if constexpr (sizeof(InT) == 2) {
#pragma unroll
        for (int kt = 0; kt < 4; ++kt)
            bh[kt] = *(const bf16x8*)((const unsigned short*)W +
                                      (size_t)(w * 16 + m) * DTOT + kt * 32 + quad * 8);
    } else {
#pragma unroll
        for (int kt = 0; kt < 4; ++kt) {
            const float* p = (const float*)W + (size_t)(w * 16 + m) * DTOT + kt * 32 + quad * 8;
#pragma unroll
            for (int j = 0; j < 8; ++j) {
                float wv = p[j];
                unsigned short hh = f2bf(wv);
                bh[kt][j] = (short)hh;
                bl[kt][j] = (short)f2bf(wv - bf2f(hh));
            }
        }
    }
    const float bias = ldval(bv + lane) + ldval(th + lane);

    // per-lane global x base: A-row m -> (t = m>>2, batch = b0 + (m&3)); this
    // wave stages K-quarter kt = w, sub-block quad.
    const InT* xbase = x + ((size_t)(m >> 2) * BATCH + (size_t)(b0 + (m & 3))) * DIN
                         + w * 32 + quad * 8;

    bf16x8* xw0 = xshv + (((m * 4 + w) * 4 + quad) * 2);   // conv write slot (hi, lo=+1)

    f32x4 rx0, rx1; bf16x8 rbx;
    auto LOAD = [&](int ch) {
        const InT* p = xbase + (size_t)ch * CH_XSTRIDE;
        if constexpr (sizeof(InT) == 2) {
            rbx = *(const bf16x8*)p;
        } else {
            rx0 = *(const f32x4*)p;
            rx1 = *(const f32x4*)((const float*)p + 4);
        }
    };
    auto PRODUCE = [&](int ch) {
        // stage this wave's K-quarter into LDS (hi/lo split for fp32)
        if constexpr (sizeof(InT) == 2) {
            xw0[0] = rbx;
        } else {
            bf16x8 ah, al;
#pragma unroll
            for (int j = 0; j < 4; ++j) {
                float xv = rx0[j];
                unsigned short hh = f2bf(xv);
                ah[j] = (short)hh; al[j] = (short)f2bf(xv - bf2f(hh));
            }
#pragma unroll
            for (int j = 0; j < 4; ++j) {
                float xv = rx1[j];
                unsigned short hh = f2bf(xv);
                ah[4 + j] = (short)hh; al[4 + j] = (short)f2bf(xv - bf2f(hh));
            }
            xw0[0] = ah; xw0[1] = al;
        }
        __syncthreads();
        // MFMA: same ladder + accumulation order as the standalone proj kernel
        f32x4 acc = {};
#pragma unroll
        for (int kt = 0; kt < 4; ++kt) {
            const bf16x8 ah = xshv[((m * 4 + kt) * 4 + quad) * 2];
            if constexpr (sizeof(InT) == 2) {
                acc = __builtin_amdgcn_mfma_f32_16x16x32_bf16(ah, bh[kt], acc, 0, 0, 0);
            } else {
                const bf16x8 al = xshv[((m * 4 + kt) * 4 + quad) * 2 + 1];
                acc = __builtin_amdgcn_mfma_f32_16x16x32_bf16(ah, bh[kt], acc, 0, 0, 0);
                acc = __builtin_amdgcn_mfma_f32_16x16x32_bf16(al, bh[kt], acc, 0, 0, 0);
                acc = __builtin_amdgcn_mfma_f32_16x16x32_bf16(ah, bl[kt], acc, 0, 0, 0);
            }
        }
        const int buf = ch & 1;
#pragma unroll
        for (int r = 0; r < 4; ++r)
            zbuf[buf][quad * 4 + r][w * 16 + m] = acc[r];
        __syncthreads();
    };

    float h = 0.f, c = 0.f, hsave = 0.f;

    LOAD(0);
    PRODUCE(0);
    LOAD(1);

    for (int ch = 0; ch < NCH; ++ch) {
        float zr[4];
#pragma unroll
        for (int dt = 0; dt < 4; ++dt)
            zr[dt] = zbuf[ch & 1][dt * 4 + w][lane] + bias;
        if (ch < NCH - 1) {
            PRODUCE(ch + 1);
            if (ch + 2 < NCH) LOAD(ch + 2);
        }
#pragma unroll
        for (int dt = 0; dt < 4; ++dt)
            qstep<BASE>(ch * 4 + dt, g, n, zr[dt], Wp, h, c, hsave, out, b,
                        a_f, a_i, a_g, a_o);
    }

    if (g == 0) {
        out[(size_t)T_STEPS * BATCH * NQ + (size_t)b * NQ + n] = h;                       // hx
        out[(size_t)T_STEPS * BATCH * NQ + (size_t)BATCH * NQ + (size_t)b * NQ + n] = c;  // cx
    }
}

__global__ __launch_bounds__(256) void qlstm_fused(
    const void* __restrict__ x_, const void* __restrict__ W_,
    const void* __restrict__ b_, const void* __restrict__ th_,
    float* __restrict__ out)
{
    __shared__ float zbuf[2][16][64];      // 8 KiB double-buffered z tile
    __shared__ bf16x8 xshv[512];           // 8 KiB staged x fragments (hi/lo)

    const int lane = threadIdx.x & 63;
    const int w    = threadIdx.x >> 6;
    const int b0   = blockIdx.x * 4;
    const int n    = lane & 15;

    const int isbf = __builtin_amdgcn_readfirstlane(detect_bf16((const unsigned int*)x_, lane));

    // runtime probe of DPP row_ror direction (wave-uniform)
    int pr  = __builtin_amdgcn_update_dpp(0, lane, 0x121, 0xF, 0xF, false);
    int p0r = __shfl(pr, 0, 64);
    const int d = (p0r == 1) ? 1 : 15;

    float Wp[16];
    if (isbf) {
        const unsigned short* W = (const unsigned short*)W_;
#pragma unroll
        for (int k = 0; k < 16; ++k)
            Wp[k] = bf2f(W[(size_t)lane * DTOT + DIN + ((n + k * d) & 15)]);
    } else {
        const float* W = (const float*)W_;
#pragma unroll
        for (int k = 0; k < 16; ++k)
            Wp[k] = W[(size_t)lane * DTOT + DIN + ((n + k * d) & 15)];
    }

    // runtime probe of DPP row_shr direction (wave-uniform) for the prefix product
    int probe = __builtin_amdgcn_update_dpp(999, lane, 0x111, 0xF, 0xF, false);
    int p2 = __shfl(probe, 2, 64);

    if (isbf) {
        if (p2 == 1) fused_main<0x110, unsigned short>((const unsigned short*)x_, (const unsigned short*)W_,
                                                       (const unsigned short*)b_, (const unsigned short*)th_,
                                                       out, b0, w, lane, Wp, zbuf, xshv);
        else         fused_main<0x100, unsigned short>((const unsigned short*)x_, (const unsigned short*)W_,
                                                       (const unsigned short*)b_, (const unsigned short*)th_,
                                                       out, b0, w, lane, Wp, zbuf, xshv);
    } else {
        if (p2 == 1) fused_main<0x110, float>((const float*)x_, (const float*)W_,
                                              (const float*)b_, (const float*)th_,
                                              out, b0, w, lane, Wp, zbuf, xshv);
        else         fused_main<0x100, float>((const float*)x_, (const float*)W_,
                                              (const float*)b_, (const float*)th_,
                                              out, b0, w, lane, Wp, zbuf, xshv);
    }
}

extern "C" void kernel_launch(void* const* d_in, const int* in_sizes, int n_in,
                              void* d_out, int out_size, void* d_ws, size_t ws_size,
                              hipStream_t stream) {
    const void* x  = d_in[0];
    const void* W  = d_in[1];
    const void* bv = d_in[2];
    const void* th = d_in[3];
    (void)d_ws; (void)ws_size;
    qlstm_fused<<<BATCH / 4, 256, 0, stream>>>(x, W, bv, th, (float*)d_out);
}

// Round 3
// 394.827 us; speedup vs baseline: 1.1849x; 1.1187x over previous
//
#include <hip/hip_runtime.h>
#include <hip/hip_bf16.h>
#include <stdint.h>

// QLSTM: T=256, B=2048, DIN=128, NQ=16, 4 gates. fp32 inputs, fp32 outputs.
// R7: R6 fused kernel + conflict-free LDS layouts.
//   - xshv relayout: slot = kt*64 + lane (writer wave w writes 64 contiguous
//     16B slots; readers read kt*64+lane contiguous). Old layout had the 16
//     m-lanes at 512B stride -> 16-way bank conflict on every b128 access
//     (SQ_LDS_BANK_CONFLICT = 4.5e7/dispatch, ~40% of kernel time).
//   - zbuf rows padded 64 -> 68 floats (quad write stride 272 % 32 = 16 ->
//     2-way aliasing = free).

#define T_STEPS 256
#define BATCH   2048
#define DIN     128
#define NQ      16
#define LCOLS   64          // 4 gates * 16 qubits
#define DTOT    144         // DIN + NQ
#define NCH     64          // T_STEPS / 4 chunks
#define CH_XSTRIDE ((size_t)4 * BATCH * DIN)   // x elements per chunk
#define ZPAD    68          // padded zbuf row

typedef __attribute__((ext_vector_type(8))) short bf16x8;
typedef __attribute__((ext_vector_type(4))) float f32x4;

__device__ __forceinline__ float bf2f(unsigned short u) {
    union { unsigned int i; float f; } v; v.i = ((unsigned int)u) << 16; return v.f;
}
__device__ __forceinline__ unsigned short f2bf(float f) {
    union { float f; unsigned int i; } v; v.f = f;
    unsigned int i = v.i;
    unsigned int r = i + 0x7fffu + ((i >> 16) & 1u);   // round-nearest-even
    return (unsigned short)(r >> 16);
}
__device__ __forceinline__ float ldval(const float* p) { return *p; }
__device__ __forceinline__ float ldval(const unsigned short* p) { return bf2f(*p); }

// ---------------- per-wave dtype detector (bf16=1, fp32=0), wave-uniform ----------------
__device__ __forceinline__ int detect_bf16(const unsigned int* __restrict__ xw, int lane) {
    int cnt = 0;
#pragma unroll
    for (int i = 0; i < 4; ++i) {
        unsigned int w = xw[lane + i * 64];
        unsigned int e = (w >> 7) & 0xFFu;
        cnt += (e >= 100u && e <= 140u) ? 1 : 0;
    }
#pragma unroll
    for (int d = 32; d > 0; d >>= 1) cnt += __shfl_down(cnt, d, 64);
    int tot = __shfl(cnt, 0, 64);
    return (tot >= 140) ? 1 : 0;
}

// ---------------- DPP helpers ----------------
template <int CTRL>
__device__ __forceinline__ float dpp_sh(float v) {   // shift w/ multiplicative identity
    int r = __builtin_amdgcn_update_dpp(__builtin_bit_cast(int, 1.0f),
                                        __builtin_bit_cast(int, v),
                                        CTRL, 0xF, 0xF, false);
    return __builtin_bit_cast(float, r);
}
template <int CTRL>
__device__ __forceinline__ float rot16(float v) {    // row rotate (pure VALU)
    int r = __builtin_amdgcn_update_dpp(0, __builtin_bit_cast(int, v),
                                        CTRL, 0xF, 0xF, false);
    return __builtin_bit_cast(float, r);
}

// ---------------- one recurrence step ----------------
template <int BASE>
__device__ __forceinline__ void qstep(int t, int g, int n, float cur,
                                      const float (&Wp)[16], float& h, float& c,
                                      float& hsave, float* __restrict__ out, int b,
                                      int a_f, int a_i, int a_g, int a_o)
{
    float h1  = rot16<0x121>(h), h2  = rot16<0x122>(h), h3  = rot16<0x123>(h);
    float h4  = rot16<0x124>(h), h5  = rot16<0x125>(h), h6  = rot16<0x126>(h), h7  = rot16<0x127>(h);
    float h8  = rot16<0x128>(h), h9  = rot16<0x129>(h), h10 = rot16<0x12A>(h), h11 = rot16<0x12B>(h);
    float h12 = rot16<0x12C>(h), h13 = rot16<0x12D>(h), h14 = rot16<0x12E>(h), h15 = rot16<0x12F>(h);

    float s0 = fmaf(Wp[0],  h,   fmaf(Wp[1],  h1,  fmaf(Wp[2],  h2,  Wp[3]  * h3)));
    float s1 = fmaf(Wp[4],  h4,  fmaf(Wp[5],  h5,  fmaf(Wp[6],  h6,  Wp[7]  * h7)));
    float s2 = fmaf(Wp[8],  h8,  fmaf(Wp[9],  h9,  fmaf(Wp[10], h10, Wp[11] * h11)));
    float s3 = fmaf(Wp[12], h12, fmaf(Wp[13], h13, fmaf(Wp[14], h14, Wp[15] * h15)));
    float z = cur + ((s0 + s1) + (s2 + s3));

    float cz = __cosf(z);
    cz *= dpp_sh<BASE + 1>(cz);
    cz *= dpp_sh<BASE + 2>(cz);
    cz *= dpp_sh<BASE + 4>(cz);
    cz *= dpp_sh<BASE + 8>(cz);

    float a = (g == 2) ? 2.f * cz : cz;
    float e = __expf(-a);
    float rr = __builtin_amdgcn_rcpf(1.f + e);
    float s = (g == 2) ? (1.f - e) * rr : rr;

    int si = __builtin_bit_cast(int, s);
    float fv = __builtin_bit_cast(float, __builtin_amdgcn_ds_bpermute(a_f, si));
    float iv = __builtin_bit_cast(float, __builtin_amdgcn_ds_bpermute(a_i, si));
    float gv = __builtin_bit_cast(float, __builtin_amdgcn_ds_bpermute(a_g, si));
    float ov = __builtin_bit_cast(float, __builtin_amdgcn_ds_bpermute(a_o, si));

    c = fmaf(fv, c, iv * gv);
    float e2 = __expf(-2.f * c);
    float tc = (1.f - e2) * __builtin_amdgcn_rcpf(1.f + e2);
    h = ov * tc;

    if ((t & 3) == g) hsave = h;
    if ((t & 3) == 3)
        out[(size_t)(t - 3 + g) * (BATCH * NQ) + (size_t)b * NQ + n] = hsave;
}

// ---------------- fused main ----------------
// xhi/xlo slot(m, kt, quad) = kt*64 + quad*16 + m = kt*64 + lane  (16B units)
//   writer: wave w, lane L -> slot w*64 + L   (contiguous 1KiB per wave)
//   reader: any wave, k-tile kt -> slot kt*64 + L (contiguous)
template <int BASE, typename InT>
__device__ __forceinline__ void fused_main(
    const InT* __restrict__ x, const InT* __restrict__ W,
    const InT* __restrict__ bv, const InT* __restrict__ th,
    float* __restrict__ out, int b0, int w, int lane,
    const float (&Wp)[16], float (*zbuf)[16][ZPAD],
    bf16x8* __restrict__ xhi, bf16x8* __restrict__ xlo)
{
    const int m = lane & 15, quad = lane >> 4;
    const int g = quad, n = m;
    const int b = b0 + w;
    const int a_f = n << 2, a_i = (16 + n) << 2, a_g = (32 + n) << 2, a_o = (48 + n) << 2;

    // B-fragments: W cols w*16 + m (this wave's output quarter), hi/lo for fp32
    bf16x8 bh[4], bl[4];
    if constexpr (sizeof(InT) == 2) {
#pragma unroll
        for (int kt = 0; kt < 4; ++kt)
            bh[kt] = *(const bf16x8*)((const unsigned short*)W +
                                      (size_t)(w * 16 + m) * DTOT + kt * 32 + quad * 8);
    } else {
#pragma unroll
        for (int kt = 0; kt < 4; ++kt) {
            const float* p = (const float*)W + (size_t)(w * 16 + m) * DTOT + kt * 32 + quad * 8;
#pragma unroll
            for (int j = 0; j < 8; ++j) {
                float wv = p[j];
                unsigned short hh = f2bf(wv);
                bh[kt][j] = (short)hh;
                bl[kt][j] = (short)f2bf(wv - bf2f(hh));
            }
        }
    }
    const float bias = ldval(bv + lane) + ldval(th + lane);

    // per-lane global x base: A-row m -> (t = m>>2, batch = b0 + (m&3)); this
    // wave stages K-quarter kt = w, sub-block quad.
    const InT* xbase = x + ((size_t)(m >> 2) * BATCH + (size_t)(b0 + (m & 3))) * DIN
                         + w * 32 + quad * 8;

    bf16x8* whi = xhi + (w * 64 + lane);
    bf16x8* wlo = xlo + (w * 64 + lane);

    f32x4 rx0, rx1; bf16x8 rbx;
    auto LOAD = [&](int ch) {
        const InT* p = xbase + (size_t)ch * CH_XSTRIDE;
        if constexpr (sizeof(InT) == 2) {
            rbx = *(const bf16x8*)p;
        } else {
            rx0 = *(const f32x4*)p;
            rx1 = *(const f32x4*)((const float*)p + 4);
        }
    };
    auto PRODUCE = [&](int ch) {
        // stage this wave's K-quarter into LDS (hi/lo split for fp32)
        if constexpr (sizeof(InT) == 2) {
            whi[0] = rbx;
        } else {
            bf16x8 ah, al;
#pragma unroll
            for (int j = 0; j < 4; ++j) {
                float xv = rx0[j];
                unsigned short hh = f2bf(xv);
                ah[j] = (short)hh; al[j] = (short)f2bf(xv - bf2f(hh));
            }
#pragma unroll
            for (int j = 0; j < 4; ++j) {
                float xv = rx1[j];
                unsigned short hh = f2bf(xv);
                ah[4 + j] = (short)hh; al[4 + j] = (short)f2bf(xv - bf2f(hh));
            }
            whi[0] = ah; wlo[0] = al;
        }
        __syncthreads();
        // MFMA: same ladder + accumulation order as the standalone proj kernel
        f32x4 acc = {};
#pragma unroll
        for (int kt = 0; kt < 4; ++kt) {
            const bf16x8 ah = xhi[kt * 64 + lane];
            if constexpr (sizeof(InT) == 2) {
                acc = __builtin_amdgcn_mfma_f32_16x16x32_bf16(ah, bh[kt], acc, 0, 0, 0);
            } else {
                const bf16x8 al = xlo[kt * 64 + lane];
                acc = __builtin_amdgcn_mfma_f32_16x16x32_bf16(ah, bh[kt], acc, 0, 0, 0);
                acc = __builtin_amdgcn_mfma_f32_16x16x32_bf16(al, bh[kt], acc, 0, 0, 0);
                acc = __builtin_amdgcn_mfma_f32_16x16x32_bf16(ah, bl[kt], acc, 0, 0, 0);
            }
        }
        const int buf = ch & 1;
#pragma unroll
        for (int r = 0; r < 4; ++r)
            zbuf[buf][quad * 4 + r][w * 16 + m] = acc[r];
        __syncthreads();
    };

    float h = 0.f, c = 0.f, hsave = 0.f;

    LOAD(0);
    PRODUCE(0);
    LOAD(1);

    for (int ch = 0; ch < NCH; ++ch) {
        float zr[4];
#pragma unroll
        for (int dt = 0; dt < 4; ++dt)
            zr[dt] = zbuf[ch & 1][dt * 4 + w][lane] + bias;
        if (ch < NCH - 1) {
            PRODUCE(ch + 1);
            if (ch + 2 < NCH) LOAD(ch + 2);
        }
#pragma unroll
        for (int dt = 0; dt < 4; ++dt)
            qstep<BASE>(ch * 4 + dt, g, n, zr[dt], Wp, h, c, hsave, out, b,
                        a_f, a_i, a_g, a_o);
    }

    if (g == 0) {
        out[(size_t)T_STEPS * BATCH * NQ + (size_t)b * NQ + n] = h;                       // hx
        out[(size_t)T_STEPS * BATCH * NQ + (size_t)BATCH * NQ + (size_t)b * NQ + n] = c;  // cx
    }
}

__global__ __launch_bounds__(256) void qlstm_fused(
    const void* __restrict__ x_, const void* __restrict__ W_,
    const void* __restrict__ b_, const void* __restrict__ th_,
    float* __restrict__ out)
{
    __shared__ float zbuf[2][16][ZPAD];    // 8.5 KiB double-buffered z tile (padded)
    __shared__ bf16x8 xhi[256];            // 4 KiB staged x fragments (hi)
    __shared__ bf16x8 xlo[256];            // 4 KiB staged x fragments (lo)

    const int lane = threadIdx.x & 63;
    const int w    = threadIdx.x >> 6;
    const int b0   = blockIdx.x * 4;
    const int n    = lane & 15;

    const int isbf = __builtin_amdgcn_readfirstlane(detect_bf16((const unsigned int*)x_, lane));

    // runtime probe of DPP row_ror direction (wave-uniform)
    int pr  = __builtin_amdgcn_update_dpp(0, lane, 0x121, 0xF, 0xF, false);
    int p0r = __shfl(pr, 0, 64);
    const int d = (p0r == 1) ? 1 : 15;

    float Wp[16];
    if (isbf) {
        const unsigned short* W = (const unsigned short*)W_;
#pragma unroll
        for (int k = 0; k < 16; ++k)
            Wp[k] = bf2f(W[(size_t)lane * DTOT + DIN + ((n + k * d) & 15)]);
    } else {
        const float* W = (const float*)W_;
#pragma unroll
        for (int k = 0; k < 16; ++k)
            Wp[k] = W[(size_t)lane * DTOT + DIN + ((n + k * d) & 15)];
    }

    // runtime probe of DPP row_shr direction (wave-uniform) for the prefix product
    int probe = __builtin_amdgcn_update_dpp(999, lane, 0x111, 0xF, 0xF, false);
    int p2 = __shfl(probe, 2, 64);

    if (isbf) {
        if (p2 == 1) fused_main<0x110, unsigned short>((const unsigned short*)x_, (const unsigned short*)W_,
                                                       (const unsigned short*)b_, (const unsigned short*)th_,
                                                       out, b0, w, lane, Wp, zbuf, xhi, xlo);
        else         fused_main<0x100, unsigned short>((const unsigned short*)x_, (const unsigned short*)W_,
                                                       (const unsigned short*)b_, (const unsigned short*)th_,
                                                       out, b0, w, lane, Wp, zbuf, xhi, xlo);
    } else {
        if (p2 == 1) fused_main<0x110, float>((const float*)x_, (const float*)W_,
                                              (const float*)b_, (const float*)th_,
                                              out, b0, w, lane, Wp, zbuf, xhi, xlo);
        else         fused_main<0x100, float>((const float*)x_, (const float*)W_,
                                              (const float*)b_, (const float*)th_,
                                              out, b0, w, lane, Wp, zbuf, xhi, xlo);
    }
}

extern "C" void kernel_launch(void* const* d_in, const int* in_sizes, int n_in,
                              void* d_out, int out_size, void* d_ws, size_t ws_size,
                              hipStream_t stream) {
    const void* x  = d_in[0];
    const void* W  = d_in[1];
    const void* bv = d_in[2];
    const void* th = d_in[3];
    (void)d_ws; (void)ws_size;
    qlstm_fused<<<BATCH / 4, 256, 0, stream>>>(x, W, bv, th, (float*)d_out);
}